// Round 8
// baseline (839.020 us; speedup 1.0000x reference)
//
#include <hip/hip_runtime.h>

typedef unsigned int uint;
typedef unsigned short ushort;
typedef unsigned long long u64;
typedef __bf16 bf16x8 __attribute__((ext_vector_type(8)));
typedef ushort ushx8 __attribute__((ext_vector_type(8)));
typedef float f32x4 __attribute__((ext_vector_type(4)));

#define ALIGN 16   // per-node slot padding (pool 16-deep MLP)
#define BSH 7      // bucket = dst >> 7 (128 nodes/bucket)

__device__ __forceinline__ ushort f2b(float f) {           // f32 -> bf16 RNE
  uint u = __builtin_bit_cast(uint, f);
  u += 0x7fffu + ((u >> 16) & 1u);
  return (ushort)(u >> 16);
}
__device__ __forceinline__ float b2f(ushort s) {
  uint u = (uint)s << 16;
  return __builtin_bit_cast(float, u);
}
__device__ __forceinline__ float blo(uint u) { return __builtin_bit_cast(float, u << 16); }
__device__ __forceinline__ float bhi(uint u) { return __builtin_bit_cast(float, u & 0xffff0000u); }
__device__ __forceinline__ int pad16(int d) { return (d + 15) & ~15; }

// ---------------- CSR build (bucketed counting sort) ----------------
__global__ void k_hist(const int* __restrict__ dst, int* __restrict__ deg, int E) {
  int e = blockIdx.x * blockDim.x + threadIdx.x;
  if (e < E) atomicAdd(&deg[dst[e]], 1);
}

// per-bucket edge count + padded-slot count, derived from deg (no atomics)
__global__ void k_bsum(const int* __restrict__ deg, int* __restrict__ bc,
                       int* __restrict__ bpad, int N, int nb) {
  int b = (int)((blockIdx.x * (size_t)blockDim.x + threadIdx.x) >> 6);
  int l = threadIdx.x & 63;
  if (b >= nb) return;
  int c = 0, p = 0;
  #pragma unroll
  for (int i = 0; i < 2; ++i) {
    int v = b * 128 + l + i * 64;
    if (v < N) { int d = deg[v]; c += d; p += pad16(d); }
  }
  #pragma unroll
  for (int s = 1; s < 64; s <<= 1) { c += __shfl_xor(c, s); p += __shfl_xor(p, s); }
  if (l == 0) { bc[b] = c; bpad[b] = p; }
}

// exclusive scans of bc and bpad (nb <= 1024); bcur (stride-16) init to bstart
__global__ void k_bscan(const int* __restrict__ bc, const int* __restrict__ bpad,
                        int* __restrict__ bstart, int* __restrict__ bcur,
                        int* __restrict__ pstartg, int nb) {
  __shared__ int s1[256], s2[256];
  int t = threadIdx.x;
  int base = t * 4;
  int lc[4], lp[4];
  int a0 = 0, a1 = 0;
  #pragma unroll
  for (int i = 0; i < 4; ++i) {
    int idx = base + i;
    lc[i] = (idx < nb) ? bc[idx] : 0;
    lp[i] = (idx < nb) ? bpad[idx] : 0;
    a0 += lc[i]; a1 += lp[i];
  }
  s1[t] = a0; s2[t] = a1;
  __syncthreads();
  for (int s = 1; s < 256; s <<= 1) {
    int v1 = 0, v2 = 0;
    if (t >= s) { v1 = s1[t - s]; v2 = s2[t - s]; }
    __syncthreads();
    s1[t] += v1; s2[t] += v2;
    __syncthreads();
  }
  int e0 = s1[t] - a0, e1 = s2[t] - a1;   // exclusive chunk bases
  #pragma unroll
  for (int i = 0; i < 4; ++i) {
    int idx = base + i;
    if (idx < nb) {
      bstart[idx] = e0; bcur[idx * 16] = e0; pstartg[idx] = e1;
      e0 += lc[i]; e1 += lp[i];
    }
  }
}

// pass A: edges -> per-bucket streams; 4B packed entry: [31:25]=dst&127, [24:0]=eid
__global__ void k_bscatter(const int* __restrict__ dst, int* __restrict__ bcur,
                           uint* __restrict__ bq, int E) {
  int e = blockIdx.x * blockDim.x + threadIdx.x;
  if (e >= E) return;
  int d = dst[e];
  int p = atomicAdd(&bcur[(d >> BSH) * 16], 1);   // absolute position
  bq[p] = ((uint)(d & 127) << 25) | (uint)e;
}

// pass B: per-bucket LDS counting sort -> ssrc/seid padded slots + off[]
__global__ __launch_bounds__(256) void k_bsort(const uint* __restrict__ bq,
                                               const int* __restrict__ edge_src,
                                               const int* __restrict__ bstart,
                                               const int* __restrict__ bc,
                                               const int* __restrict__ pstartg,
                                               int* __restrict__ ssrc,
                                               int* __restrict__ seid,
                                               int* __restrict__ off, int N) {
  __shared__ int cnt[128], cur[128], pst[128], tmp[128];
  int b = blockIdx.x;
  int t = threadIdx.x;
  int e0 = bstart[b], ne = bc[b], s0 = pstartg[b];
  if (t < 128) cnt[t] = 0;
  __syncthreads();
  for (int i = t; i < ne; i += 256) atomicAdd(&cnt[bq[e0 + i] >> 25], 1);
  __syncthreads();
  int myc = (t < 128) ? cnt[t] : 0;
  int myp = pad16(myc);
  if (t < 128) tmp[t] = myp;
  __syncthreads();
  for (int s = 1; s < 128; s <<= 1) {
    int v = 0;
    if (t >= s && t < 128) v = tmp[t - s];
    __syncthreads();
    if (t < 128) tmp[t] += v;
    __syncthreads();
  }
  if (t < 128) {
    pst[t] = tmp[t] - myp;
    cur[t] = pst[t];
    int v = b * 128 + t;
    if (v < N) off[v] = s0 + pst[t];
  }
  __syncthreads();
  for (int i = t; i < ne; i += 256) {
    uint v = bq[e0 + i];
    int ln = (int)(v >> 25);
    int eid = (int)(v & 0x01FFFFFFu);
    int p = atomicAdd(&cur[ln], 1);
    ssrc[s0 + p] = edge_src[eid];       // L2/L3-hot random 4B gather
    seid[s0 + p] = eid;
  }
  __syncthreads();
  if (t < 128) {
    int end = pst[t] + myp;
    for (int p = pst[t] + myc; p < end; ++p) {
      ssrc[s0 + p] = N;                 // zero-row sentinel
      seid[s0 + p] = -1;                // pad marker
    }
  }
}

// ------------- edge-feature segment sum, direct f32 gather (8 rows in flight) ----
// Eb[row][0..15]=sums, [16]=deg, rest 0; rows >= N all-zero.
__global__ void k_acc16f(const float* __restrict__ ef, const int* __restrict__ off,
                         const int* __restrict__ deg, const int* __restrict__ seid,
                         ushort* __restrict__ Eb, int N, int Mpad) {
  int wid = (int)((blockIdx.x * (size_t)blockDim.x + threadIdx.x) >> 6);
  int l = threadIdx.x & 63;
  if (wid >= Mpad) return;
  if (wid >= N) {
    if (l < 16) *(uint*)(Eb + (size_t)wid * 32 + l * 2) = 0u;
    return;
  }
  int o = off[wid];
  int d = deg[wid];
  int dp = (d + 7) & ~7;            // <= pad16(d), pads have eid=-1 -> 0
  int i_sub = l >> 3, jj = l & 7;   // 8 rows x 8 lanes (float2 each = 64B row)
  const float2* ef2 = (const float2*)ef;
  float ax = 0.f, ay = 0.f;
  for (int base = 0; base < dp; base += 8) {
    int eid = seid[o + base + i_sub];
    bool valid = eid >= 0;
    int ec = valid ? eid : 0;
    float2 v = ef2[(size_t)ec * 8 + jj];
    ax += valid ? v.x : 0.f;
    ay += valid ? v.y : 0.f;
  }
  ax += __shfl_xor(ax, 8);  ay += __shfl_xor(ay, 8);
  ax += __shfl_xor(ax, 16); ay += __shfl_xor(ay, 16);
  ax += __shfl_xor(ax, 32); ay += __shfl_xor(ay, 32);
  if (l < 16) {
    uint out;
    if (l < 8)       out = (uint)f2b(ax) | ((uint)f2b(ay) << 16);
    else if (l == 8) out = (uint)f2b((float)d);            // (deg, 0)
    else             out = 0u;
    *(uint*)(Eb + (size_t)wid * 32 + l * 2) = out;
  }
}

// transposed bf16 weights: Wtn[c][k] (K=160: w_n2l ; w_e2l ; b_e2l ; 0), Wtc/Wto[c][k] (K=128)
__global__ void k_wt(const float* __restrict__ w_n2l, const float* __restrict__ w_e2l,
                     const float* __restrict__ b_e2l, const float* __restrict__ w_conv,
                     const float* __restrict__ w_out,
                     ushort* __restrict__ Wtn, ushort* __restrict__ Wtc, ushort* __restrict__ Wto) {
  int c = blockIdx.x;
  int k = threadIdx.x;
  int s = blockIdx.y;
  if (s == 0) {
    if (k < 160) {
      float v = (k < 128) ? w_n2l[(size_t)k * 128 + c]
              : (k < 144) ? w_e2l[(size_t)(k - 128) * 128 + c]
              : (k == 144) ? b_e2l[c] : 0.f;
      Wtn[(size_t)c * 160 + k] = f2b(v);
    }
  } else if (s == 1) {
    if (k < 128) Wtc[(size_t)c * 128 + k] = f2b(w_conv[(size_t)k * 128 + c]);
  } else {
    if (k < 128) Wto[(size_t)c * 128 + k] = f2b(w_out[(size_t)k * 128 + c]);
  }
}

// ---------------- MFMA GEMM mode 0 (n2l), A built on the fly ----------------
__global__ __launch_bounds__(256) void k_mm0(
    const float* __restrict__ nf, const ushort* __restrict__ Eb,
    const ushort* __restrict__ Wt, const float* __restrict__ bias,
    const float* __restrict__ bias2, ushort* __restrict__ C,
    ushort* __restrict__ C2, int nrows) {
  const int KA = 160;
  int l = threadIdx.x & 63;
  int w = threadIdx.x >> 6;
  int lr = l & 15, lg = l >> 4;
  size_t row0 = (size_t)blockIdx.x * 128 + (size_t)w * 32;

  bf16x8 a[2][5];
  #pragma unroll
  for (int tr = 0; tr < 2; ++tr) {
    size_t row = row0 + tr * 16 + lr;
    bool valid = row < (size_t)nrows;
    size_t rowc = valid ? row : 0;
    const float* p = nf + rowc * 128 + lg * 8;
    #pragma unroll
    for (int ks = 0; ks < 4; ++ks) {
      float4 q0 = *(const float4*)(p + ks * 32);
      float4 q1 = *(const float4*)(p + ks * 32 + 4);
      ushx8 u;
      u[0] = valid ? f2b(q0.x) : (ushort)0; u[1] = valid ? f2b(q0.y) : (ushort)0;
      u[2] = valid ? f2b(q0.z) : (ushort)0; u[3] = valid ? f2b(q0.w) : (ushort)0;
      u[4] = valid ? f2b(q1.x) : (ushort)0; u[5] = valid ? f2b(q1.y) : (ushort)0;
      u[6] = valid ? f2b(q1.z) : (ushort)0; u[7] = valid ? f2b(q1.w) : (ushort)0;
      a[tr][ks] = __builtin_bit_cast(bf16x8, u);
    }
    a[tr][4] = *(const bf16x8*)(const void*)(Eb + row * 32 + lg * 8);  // pad rows zero
  }

  f32x4 acc[2][8];
  #pragma unroll
  for (int tr = 0; tr < 2; ++tr)
    #pragma unroll
    for (int tc = 0; tc < 8; ++tc)
      acc[tr][tc] = (f32x4){0.f, 0.f, 0.f, 0.f};

  #pragma unroll
  for (int tc = 0; tc < 8; ++tc) {
    const ushort* p = Wt + (size_t)(tc * 16 + lr) * KA + lg * 8;
    bf16x8 b[5];
    #pragma unroll
    for (int ks = 0; ks < 5; ++ks)
      b[ks] = *(const bf16x8*)(const void*)(p + ks * 32);
    #pragma unroll
    for (int ks = 0; ks < 5; ++ks) {
      acc[0][tc] = __builtin_amdgcn_mfma_f32_16x16x32_bf16(a[0][ks], b[ks], acc[0][tc], 0, 0, 0);
      acc[1][tc] = __builtin_amdgcn_mfma_f32_16x16x32_bf16(a[1][ks], b[ks], acc[1][tc], 0, 0, 0);
    }
  }

  #pragma unroll
  for (int tc = 0; tc < 8; ++tc) {
    int col = tc * 16 + lr;
    float bv = bias[col];
    float b2v = bias2[col];
    #pragma unroll
    for (int tr = 0; tr < 2; ++tr) {
      size_t rbase = row0 + tr * 16 + lg * 4;
      #pragma unroll
      for (int e = 0; e < 4; ++e) {
        size_t r = rbase + e;
        size_t idx = r * 128 + col;
        if (r < (size_t)nrows) {
          float vb = acc[tr][tc][e] + bv;
          C[idx] = f2b(fmaxf(vb, 0.f));
          C2[idx] = f2b(vb + b2v);
        } else {
          C[idx] = 0; C2[idx] = 0;       // row N = pool sentinel stays zero
        }
      }
    }
  }
}

// ---------------- MFMA GEMM modes 1/2: C = [relu](A@Wt^T [+ bias]) ----------------
template<int MODE>   // 1: conv (no bias, no relu)   2: out (bias + relu)
__global__ __launch_bounds__(256) void k_mm(
    const ushort* __restrict__ A, const ushort* __restrict__ Wt,
    const float* __restrict__ bias, ushort* __restrict__ C) {
  const int KA = 128;
  int l = threadIdx.x & 63;
  int w = threadIdx.x >> 6;
  int lr = l & 15, lg = l >> 4;
  size_t row0 = (size_t)blockIdx.x * 128 + (size_t)w * 32;

  bf16x8 a[2][4];
  #pragma unroll
  for (int tr = 0; tr < 2; ++tr) {
    const ushort* p = A + (row0 + tr * 16 + lr) * KA + lg * 8;
    #pragma unroll
    for (int ks = 0; ks < 4; ++ks)
      a[tr][ks] = *(const bf16x8*)(const void*)(p + ks * 32);
  }

  f32x4 acc[2][8];
  #pragma unroll
  for (int tr = 0; tr < 2; ++tr)
    #pragma unroll
    for (int tc = 0; tc < 8; ++tc)
      acc[tr][tc] = (f32x4){0.f, 0.f, 0.f, 0.f};

  #pragma unroll
  for (int tc = 0; tc < 8; ++tc) {
    const ushort* p = Wt + (size_t)(tc * 16 + lr) * KA + lg * 8;
    bf16x8 b[4];
    #pragma unroll
    for (int ks = 0; ks < 4; ++ks)
      b[ks] = *(const bf16x8*)(const void*)(p + ks * 32);
    #pragma unroll
    for (int ks = 0; ks < 4; ++ks) {
      acc[0][tc] = __builtin_amdgcn_mfma_f32_16x16x32_bf16(a[0][ks], b[ks], acc[0][tc], 0, 0, 0);
      acc[1][tc] = __builtin_amdgcn_mfma_f32_16x16x32_bf16(a[1][ks], b[ks], acc[1][tc], 0, 0, 0);
    }
  }

  #pragma unroll
  for (int tc = 0; tc < 8; ++tc) {
    int col = tc * 16 + lr;
    float bv = (MODE == 2) ? bias[col] : 0.f;
    #pragma unroll
    for (int tr = 0; tr < 2; ++tr) {
      size_t rbase = row0 + tr * 16 + lg * 4;
      #pragma unroll
      for (int e = 0; e < 4; ++e) {
        float v = acc[tr][tc][e];
        size_t idx = (rbase + e) * 128 + col;
        if (MODE == 1) C[idx] = f2b(v);
        else           C[idx] = f2b(fmaxf(v + bv, 0.f));
      }
    }
  }
}

// ------------- pool+update: hb[v] = relu(sum_in hwb[src] + im2b[v]) ----------
__global__ void k_pool_b(const ushort* __restrict__ hwb, const int* __restrict__ off,
                         const int* __restrict__ deg, const int* __restrict__ ssrc,
                         const ushort* __restrict__ im2b, ushort* __restrict__ hb, int N) {
  int wid = (int)((blockIdx.x * (size_t)blockDim.x + threadIdx.x) >> 6);
  int l = threadIdx.x & 63;
  if (wid >= N) return;
  int o = off[wid];
  int dp = (deg[wid] + (ALIGN - 1)) & ~(ALIGN - 1);
  const uint* __restrict__ rows = (const uint*)hwb;
  float ax = 0.f, ay = 0.f;
  for (int i = 0; i < dp; i += 16) {
    int s[16];
    #pragma unroll
    for (int j = 0; j < 16; ++j) s[j] = ssrc[o + i + j];
    uint u[16];
    #pragma unroll
    for (int j = 0; j < 16; ++j) u[j] = rows[(size_t)s[j] * 64 + l];
    #pragma unroll
    for (int j = 0; j < 16; ++j) { ax += blo(u[j]); ay += bhi(u[j]); }
  }
  uint m = ((const uint*)im2b)[(size_t)wid * 64 + l];
  float rx = fmaxf(ax + blo(m), 0.f);
  float ry = fmaxf(ay + bhi(m), 0.f);
  ((uint*)hb)[(size_t)wid * 64 + l] = (uint)f2b(rx) | ((uint)f2b(ry) << 16);
}

// ------------- graph pooling: y[g] = relu(sum_{rows of g} actb[row]) ----------
__global__ void k_graphpool_b(const ushort* __restrict__ act, const int* __restrict__ gid,
                              float* __restrict__ out, int N) {
  __shared__ int s_lo, s_hi;
  __shared__ float red[8][32];
  int g = blockIdx.x;
  int chunk = blockIdx.y;
  int t = threadIdx.x;
  if (t == 0) {
    int lo = 0, hi = N;
    while (lo < hi) { int mid = (lo + hi) >> 1; if (gid[mid] < g) lo = mid + 1; else hi = mid; }
    s_lo = lo;
    lo = 0; hi = N;
    while (lo < hi) { int mid = (lo + hi) >> 1; if (gid[mid] < g + 1) lo = mid + 1; else hi = mid; }
    s_hi = lo;
  }
  __syncthreads();
  int c = chunk * 32 + (t & 31);
  int rid = t >> 5;
  float acc = 0.f;
  for (int r = s_lo + rid; r < s_hi; r += 8)
    acc += b2f(act[(size_t)r * 128 + c]);
  red[rid][t & 31] = acc;
  __syncthreads();
  if (rid == 0) {
    float s = 0.f;
    #pragma unroll
    for (int i = 0; i < 8; ++i) s += red[i][t & 31];
    out[(size_t)g * 128 + c] = fmaxf(s, 0.f);
  }
}

extern "C" void kernel_launch(void* const* d_in, const int* in_sizes, int n_in,
                              void* d_out, int out_size, void* d_ws, size_t ws_size,
                              hipStream_t stream) {
  const float* node_feat = (const float*)d_in[0];
  const float* edge_feat = (const float*)d_in[1];
  const int*   edge_src  = (const int*)d_in[2];
  const int*   edge_dst  = (const int*)d_in[3];
  const int*   graph_ids = (const int*)d_in[4];
  const float* w_n2l  = (const float*)d_in[5];
  const float* b_n2l  = (const float*)d_in[6];
  const float* w_e2l  = (const float*)d_in[7];
  const float* b_e2l  = (const float*)d_in[8];
  const float* w_conv = (const float*)d_in[9];
  const float* b_conv = (const float*)d_in[10];
  const float* w_out  = (const float*)d_in[11];
  const float* b_out  = (const float*)d_in[12];

  int N = in_sizes[0] / 128;
  int E = in_sizes[2];
  int Mpad = ((N + 128) / 128) * 128;          // >= N+1 (row N = pool sentinel)
  int cap = E + (ALIGN - 1) * N;               // padded slot capacity upper bound
  int nb = (N + 127) >> BSH;                   // buckets

  // ---- workspace carve ----
  ushort* Eb   = (ushort*)d_ws;                     // [Mpad][32]
  ushort* hb   = Eb   + (size_t)Mpad * 32;          // [Mpad][128]
  ushort* hwb  = hb   + (size_t)Mpad * 128;
  ushort* im2b = hwb  + (size_t)Mpad * 128;
  ushort* actb = im2b + (size_t)Mpad * 128;
  ushort* Wtn  = actb + (size_t)Mpad * 128;         // [128][160]
  ushort* Wtc  = Wtn + 128 * 160;                   // [128][128]
  ushort* Wto  = Wtc + 128 * 128;
  int* deg     = (int*)(Wto + 128 * 128);           // [N]
  int* off     = deg + N;                           // [N]
  int* bc      = off + N;                           // [nb]
  int* bpad    = bc + nb;
  int* bstart  = bpad + nb;
  int* pstartg = bstart + nb;
  int* bcur    = pstartg + nb;                      // [nb*16] (line-spread counters)
  uint* bq     = (uint*)(bcur + (size_t)nb * 16);   // [E] packed {dst&127, eid}
  int* ssrc    = (int*)(bq + E);                    // [cap]
  int* seid    = ssrc + cap;                        // [cap]

  hipMemsetAsync(deg, 0, (size_t)N * sizeof(int), stream);

  int eb = (E + 255) / 256;
  k_hist<<<eb, 256, 0, stream>>>(edge_dst, deg, E);
  k_bsum<<<(nb * 64 + 255) / 256, 256, 0, stream>>>(deg, bc, bpad, N, nb);
  k_bscan<<<1, 256, 0, stream>>>(bc, bpad, bstart, bcur, pstartg, nb);
  k_bscatter<<<eb, 256, 0, stream>>>(edge_dst, bcur, bq, E);
  k_bsort<<<nb, 256, 0, stream>>>(bq, edge_src, bstart, bc, pstartg, ssrc, seid, off, N);
  k_acc16f<<<Mpad / 4, 256, 0, stream>>>(edge_feat, off, deg, seid, Eb, N, Mpad);
  k_wt<<<dim3(128, 3), 256, 0, stream>>>(w_n2l, w_e2l, b_e2l, w_conv, w_out, Wtn, Wtc, Wto);

  int gB = Mpad / 128;
  k_mm0<<<gB, 256, 0, stream>>>(node_feat, Eb, Wtn, b_n2l, b_conv, hb, im2b, N);
  for (int it = 0; it < 3; ++it) {
    k_mm<1><<<gB, 256, 0, stream>>>(hb, Wtc, nullptr, hwb);
    k_pool_b<<<((size_t)N * 64 + 255) / 256, 256, 0, stream>>>(hwb, off, deg, ssrc, im2b, hb, N);
  }
  k_mm<2><<<gB, 256, 0, stream>>>(hb, Wto, b_out, actb);

  dim3 gp(out_size / 128, 4);
  k_graphpool_b<<<gp, 256, 0, stream>>>(actb, graph_ids, (float*)d_out, N);
}

// Round 9
// 740.759 us; speedup vs baseline: 1.1326x; 1.1326x over previous
//
#include <hip/hip_runtime.h>

typedef unsigned int uint;
typedef unsigned short ushort;
typedef __bf16 bf16x8 __attribute__((ext_vector_type(8)));
typedef ushort ushx8 __attribute__((ext_vector_type(8)));
typedef float f32x4 __attribute__((ext_vector_type(4)));

#define ALIGN 16    // per-node slot padding (pool 16-deep MLP)
#define BSH 7       // bucket = dst >> 7 (128 nodes/bucket)
#define NBMAX 1024  // max buckets (N <= 131072)
#define CHUNK 8192  // edges per WG in binned scatter

__device__ __forceinline__ ushort f2b(float f) {           // f32 -> bf16 RNE
  uint u = __builtin_bit_cast(uint, f);
  u += 0x7fffu + ((u >> 16) & 1u);
  return (ushort)(u >> 16);
}
__device__ __forceinline__ float b2f(ushort s) {
  uint u = (uint)s << 16;
  return __builtin_bit_cast(float, u);
}
__device__ __forceinline__ float blo(uint u) { return __builtin_bit_cast(float, u << 16); }
__device__ __forceinline__ float bhi(uint u) { return __builtin_bit_cast(float, u & 0xffff0000u); }
__device__ __forceinline__ int pad16(int d) { return (d + 15) & ~15; }

// ---------------- CSR build (WG-binned bucketed counting sort) ----------------
// per-bucket histogram, LDS pre-aggregated (one global atomic per WG x bucket)
__global__ void k_bhist(const int* __restrict__ dst, int* __restrict__ bc, int E, int nb) {
  __shared__ int cnt[NBMAX];
  int t = threadIdx.x;
  for (int i = t; i < nb; i += 256) cnt[i] = 0;
  __syncthreads();
  int begin = blockIdx.x * CHUNK;
  int end = min(begin + CHUNK, E);
  for (int i = begin + t; i < end; i += 256)
    atomicAdd(&cnt[dst[i] >> BSH], 1);
  __syncthreads();
  for (int i = t; i < nb; i += 256)
    if (cnt[i]) atomicAdd(&bc[i], cnt[i]);
}

// exclusive scan of in[nb] -> outs[nb]; optionally init bcur[i*16] (nb <= 1024)
__global__ void k_scan(const int* __restrict__ in, int* __restrict__ outs,
                       int* __restrict__ bcur, int nb) {
  __shared__ int s1[256];
  int t = threadIdx.x;
  int base = t * 4;
  int lv[4];
  int a = 0;
  #pragma unroll
  for (int i = 0; i < 4; ++i) {
    int idx = base + i;
    lv[i] = (idx < nb) ? in[idx] : 0;
    a += lv[i];
  }
  s1[t] = a;
  __syncthreads();
  for (int s = 1; s < 256; s <<= 1) {
    int v = 0;
    if (t >= s) v = s1[t - s];
    __syncthreads();
    s1[t] += v;
    __syncthreads();
  }
  int e = s1[t] - a;
  #pragma unroll
  for (int i = 0; i < 4; ++i) {
    int idx = base + i;
    if (idx < nb) {
      outs[idx] = e;
      if (bcur) bcur[idx * 16] = e;
      e += lv[i];
    }
  }
}

// binned scatter: stage chunk in LDS, count, reserve per-bucket ranges (1 global
// atomic each), place at base+rank -> dense bursts, writeback ~= payload.
// packed entry: [28:22]=dst&127, [21:0]=eid  (E < 4M)
__global__ __launch_bounds__(256) void k_bscatter(const int* __restrict__ dst,
                                                  int* __restrict__ bcur,
                                                  uint* __restrict__ bq, int E, int nb) {
  __shared__ int sd[CHUNK];          // 32 KB
  __shared__ int cnt[NBMAX], cur[NBMAX];
  int t = threadIdx.x;
  for (int i = t; i < nb; i += 256) cnt[i] = 0;
  __syncthreads();
  int begin = blockIdx.x * CHUNK;
  int end = min(begin + CHUNK, E);
  for (int i = begin + t; i < end; i += 256) {
    int d = dst[i];
    sd[i - begin] = d;
    atomicAdd(&cnt[d >> BSH], 1);
  }
  __syncthreads();
  for (int i = t; i < nb; i += 256) {
    int c = cnt[i];
    cur[i] = c ? atomicAdd(&bcur[i * 16], c) : 0;
  }
  __syncthreads();
  for (int i = begin + t; i < end; i += 256) {
    int d = sd[i - begin];
    int p = atomicAdd(&cur[d >> BSH], 1);
    bq[p] = ((uint)(d & 127) << 22) | (uint)i;
  }
}

// per-bucket: count nodes -> deg (coalesced), bpad[b] = sum pad16(deg)
__global__ void k_bcount(const uint* __restrict__ bq, const int* __restrict__ bstart,
                         const int* __restrict__ bc, int* __restrict__ deg,
                         int* __restrict__ bpad, int N) {
  __shared__ int cnt[128];
  __shared__ int red2[2];
  int b = blockIdx.x;
  int t = threadIdx.x;
  if (t < 128) cnt[t] = 0;
  __syncthreads();
  int e0 = bstart[b], ne = bc[b];
  for (int i = t; i < ne; i += 256) atomicAdd(&cnt[(bq[e0 + i] >> 22) & 127], 1);
  __syncthreads();
  int p = 0;
  if (t < 128) {
    int v = b * 128 + t;
    int c = cnt[t];
    if (v < N) { deg[v] = c; p = pad16(c); }
  }
  #pragma unroll
  for (int s = 1; s < 64; s <<= 1) p += __shfl_xor(p, s);
  if (t == 0) red2[0] = p;
  if (t == 64) red2[1] = p;
  __syncthreads();
  if (t == 0) bpad[b] = red2[0] + red2[1];
}

// per-bucket place: padded slots (ssrc gathers edge_src, L2/L3-hot) + off[]
__global__ __launch_bounds__(256) void k_bplace(const uint* __restrict__ bq,
                                                const int* __restrict__ edge_src,
                                                const int* __restrict__ bstart,
                                                const int* __restrict__ bc,
                                                const int* __restrict__ pstartg,
                                                const int* __restrict__ deg,
                                                int* __restrict__ ssrc,
                                                int* __restrict__ seid,
                                                int* __restrict__ off, int N) {
  __shared__ int pst[128], cur[128], tmp[128];
  int b = blockIdx.x;
  int t = threadIdx.x;
  int e0 = bstart[b], ne = bc[b], s0 = pstartg[b];
  int myc = 0, myp = 0;
  if (t < 128) {
    int v = b * 128 + t;
    myc = (v < N) ? deg[v] : 0;
    myp = pad16(myc);
    tmp[t] = myp;
  }
  __syncthreads();
  for (int s = 1; s < 128; s <<= 1) {
    int v = 0;
    if (t >= s && t < 128) v = tmp[t - s];
    __syncthreads();
    if (t < 128) tmp[t] += v;
    __syncthreads();
  }
  if (t < 128) {
    pst[t] = tmp[t] - myp;
    cur[t] = pst[t];
    int v = b * 128 + t;
    if (v < N) off[v] = s0 + pst[t];
  }
  __syncthreads();
  for (int i = t; i < ne; i += 256) {
    uint v = bq[e0 + i];
    int ln = (int)((v >> 22) & 127);
    int eid = (int)(v & 0x3FFFFFu);
    int p = atomicAdd(&cur[ln], 1);
    ssrc[s0 + p] = edge_src[eid];
    seid[s0 + p] = eid;
  }
  __syncthreads();
  if (t < 128) {
    int end = pst[t] + myp;
    for (int p = pst[t] + myc; p < end; ++p) {
      ssrc[s0 + p] = N;                 // zero-row sentinel
      seid[s0 + p] = -1;                // pad marker
    }
  }
}

// ------------- edge-feature segment sum, direct f32 gather (8 rows in flight) ----
__global__ void k_acc16f(const float* __restrict__ ef, const int* __restrict__ off,
                         const int* __restrict__ deg, const int* __restrict__ seid,
                         ushort* __restrict__ Eb, int N, int Mpad) {
  int wid = (int)((blockIdx.x * (size_t)blockDim.x + threadIdx.x) >> 6);
  int l = threadIdx.x & 63;
  if (wid >= Mpad) return;
  if (wid >= N) {
    if (l < 16) *(uint*)(Eb + (size_t)wid * 32 + l * 2) = 0u;
    return;
  }
  int o = off[wid];
  int d = deg[wid];
  int dp = (d + 7) & ~7;            // <= pad16(d), pads have eid=-1 -> 0
  int i_sub = l >> 3, jj = l & 7;   // 8 rows x 8 lanes (float2 each = 64B row)
  const float2* ef2 = (const float2*)ef;
  float ax = 0.f, ay = 0.f;
  for (int base = 0; base < dp; base += 8) {
    int eid = seid[o + base + i_sub];
    bool valid = eid >= 0;
    int ec = valid ? eid : 0;
    float2 v = ef2[(size_t)ec * 8 + jj];
    ax += valid ? v.x : 0.f;
    ay += valid ? v.y : 0.f;
  }
  ax += __shfl_xor(ax, 8);  ay += __shfl_xor(ay, 8);
  ax += __shfl_xor(ax, 16); ay += __shfl_xor(ay, 16);
  ax += __shfl_xor(ax, 32); ay += __shfl_xor(ay, 32);
  if (l < 16) {
    uint out;
    if (l < 8)       out = (uint)f2b(ax) | ((uint)f2b(ay) << 16);
    else if (l == 8) out = (uint)f2b((float)d);            // (deg, 0)
    else             out = 0u;
    *(uint*)(Eb + (size_t)wid * 32 + l * 2) = out;
  }
}

// transposed bf16 weights: Wtn[c][k] (K=160: w_n2l ; w_e2l ; b_e2l ; 0), Wtc/Wto[c][k] (K=128)
__global__ void k_wt(const float* __restrict__ w_n2l, const float* __restrict__ w_e2l,
                     const float* __restrict__ b_e2l, const float* __restrict__ w_conv,
                     const float* __restrict__ w_out,
                     ushort* __restrict__ Wtn, ushort* __restrict__ Wtc, ushort* __restrict__ Wto) {
  int c = blockIdx.x;
  int k = threadIdx.x;
  int s = blockIdx.y;
  if (s == 0) {
    if (k < 160) {
      float v = (k < 128) ? w_n2l[(size_t)k * 128 + c]
              : (k < 144) ? w_e2l[(size_t)(k - 128) * 128 + c]
              : (k == 144) ? b_e2l[c] : 0.f;
      Wtn[(size_t)c * 160 + k] = f2b(v);
    }
  } else if (s == 1) {
    if (k < 128) Wtc[(size_t)c * 128 + k] = f2b(w_conv[(size_t)k * 128 + c]);
  } else {
    if (k < 128) Wto[(size_t)c * 128 + k] = f2b(w_out[(size_t)k * 128 + c]);
  }
}

// ---------------- MFMA GEMM mode 0 (n2l), A built on the fly ----------------
__global__ __launch_bounds__(256) void k_mm0(
    const float* __restrict__ nf, const ushort* __restrict__ Eb,
    const ushort* __restrict__ Wt, const float* __restrict__ bias,
    const float* __restrict__ bias2, ushort* __restrict__ C,
    ushort* __restrict__ C2, int nrows) {
  const int KA = 160;
  int l = threadIdx.x & 63;
  int w = threadIdx.x >> 6;
  int lr = l & 15, lg = l >> 4;
  size_t row0 = (size_t)blockIdx.x * 128 + (size_t)w * 32;

  bf16x8 a[2][5];
  #pragma unroll
  for (int tr = 0; tr < 2; ++tr) {
    size_t row = row0 + tr * 16 + lr;
    bool valid = row < (size_t)nrows;
    size_t rowc = valid ? row : 0;
    const float* p = nf + rowc * 128 + lg * 8;
    #pragma unroll
    for (int ks = 0; ks < 4; ++ks) {
      float4 q0 = *(const float4*)(p + ks * 32);
      float4 q1 = *(const float4*)(p + ks * 32 + 4);
      ushx8 u;
      u[0] = valid ? f2b(q0.x) : (ushort)0; u[1] = valid ? f2b(q0.y) : (ushort)0;
      u[2] = valid ? f2b(q0.z) : (ushort)0; u[3] = valid ? f2b(q0.w) : (ushort)0;
      u[4] = valid ? f2b(q1.x) : (ushort)0; u[5] = valid ? f2b(q1.y) : (ushort)0;
      u[6] = valid ? f2b(q1.z) : (ushort)0; u[7] = valid ? f2b(q1.w) : (ushort)0;
      a[tr][ks] = __builtin_bit_cast(bf16x8, u);
    }
    a[tr][4] = *(const bf16x8*)(const void*)(Eb + row * 32 + lg * 8);  // pad rows zero
  }

  f32x4 acc[2][8];
  #pragma unroll
  for (int tr = 0; tr < 2; ++tr)
    #pragma unroll
    for (int tc = 0; tc < 8; ++tc)
      acc[tr][tc] = (f32x4){0.f, 0.f, 0.f, 0.f};

  #pragma unroll
  for (int tc = 0; tc < 8; ++tc) {
    const ushort* p = Wt + (size_t)(tc * 16 + lr) * KA + lg * 8;
    bf16x8 b[5];
    #pragma unroll
    for (int ks = 0; ks < 5; ++ks)
      b[ks] = *(const bf16x8*)(const void*)(p + ks * 32);
    #pragma unroll
    for (int ks = 0; ks < 5; ++ks) {
      acc[0][tc] = __builtin_amdgcn_mfma_f32_16x16x32_bf16(a[0][ks], b[ks], acc[0][tc], 0, 0, 0);
      acc[1][tc] = __builtin_amdgcn_mfma_f32_16x16x32_bf16(a[1][ks], b[ks], acc[1][tc], 0, 0, 0);
    }
  }

  #pragma unroll
  for (int tc = 0; tc < 8; ++tc) {
    int col = tc * 16 + lr;
    float bv = bias[col];
    float b2v = bias2[col];
    #pragma unroll
    for (int tr = 0; tr < 2; ++tr) {
      size_t rbase = row0 + tr * 16 + lg * 4;
      #pragma unroll
      for (int e = 0; e < 4; ++e) {
        size_t r = rbase + e;
        size_t idx = r * 128 + col;
        if (r < (size_t)nrows) {
          float vb = acc[tr][tc][e] + bv;
          C[idx] = f2b(fmaxf(vb, 0.f));
          C2[idx] = f2b(vb + b2v);
        } else {
          C[idx] = 0; C2[idx] = 0;       // row N = pool sentinel stays zero
        }
      }
    }
  }
}

// ---------------- MFMA GEMM modes 1/2: C = [relu](A@Wt^T [+ bias]) ----------------
template<int MODE>   // 1: conv (no bias, no relu)   2: out (bias + relu)
__global__ __launch_bounds__(256) void k_mm(
    const ushort* __restrict__ A, const ushort* __restrict__ Wt,
    const float* __restrict__ bias, ushort* __restrict__ C) {
  const int KA = 128;
  int l = threadIdx.x & 63;
  int w = threadIdx.x >> 6;
  int lr = l & 15, lg = l >> 4;
  size_t row0 = (size_t)blockIdx.x * 128 + (size_t)w * 32;

  bf16x8 a[2][4];
  #pragma unroll
  for (int tr = 0; tr < 2; ++tr) {
    const ushort* p = A + (row0 + tr * 16 + lr) * KA + lg * 8;
    #pragma unroll
    for (int ks = 0; ks < 4; ++ks)
      a[tr][ks] = *(const bf16x8*)(const void*)(p + ks * 32);
  }

  f32x4 acc[2][8];
  #pragma unroll
  for (int tr = 0; tr < 2; ++tr)
    #pragma unroll
    for (int tc = 0; tc < 8; ++tc)
      acc[tr][tc] = (f32x4){0.f, 0.f, 0.f, 0.f};

  #pragma unroll
  for (int tc = 0; tc < 8; ++tc) {
    const ushort* p = Wt + (size_t)(tc * 16 + lr) * KA + lg * 8;
    bf16x8 b[4];
    #pragma unroll
    for (int ks = 0; ks < 4; ++ks)
      b[ks] = *(const bf16x8*)(const void*)(p + ks * 32);
    #pragma unroll
    for (int ks = 0; ks < 4; ++ks) {
      acc[0][tc] = __builtin_amdgcn_mfma_f32_16x16x32_bf16(a[0][ks], b[ks], acc[0][tc], 0, 0, 0);
      acc[1][tc] = __builtin_amdgcn_mfma_f32_16x16x32_bf16(a[1][ks], b[ks], acc[1][tc], 0, 0, 0);
    }
  }

  #pragma unroll
  for (int tc = 0; tc < 8; ++tc) {
    int col = tc * 16 + lr;
    float bv = (MODE == 2) ? bias[col] : 0.f;
    #pragma unroll
    for (int tr = 0; tr < 2; ++tr) {
      size_t rbase = row0 + tr * 16 + lg * 4;
      #pragma unroll
      for (int e = 0; e < 4; ++e) {
        float v = acc[tr][tc][e];
        size_t idx = (rbase + e) * 128 + col;
        if (MODE == 1) C[idx] = f2b(v);
        else           C[idx] = f2b(fmaxf(v + bv, 0.f));
      }
    }
  }
}

// ------------- pool+update: hb[v] = relu(sum_in hwb[src] + im2b[v]) ----------
__global__ void k_pool_b(const ushort* __restrict__ hwb, const int* __restrict__ off,
                         const int* __restrict__ deg, const int* __restrict__ ssrc,
                         const ushort* __restrict__ im2b, ushort* __restrict__ hb, int N) {
  int wid = (int)((blockIdx.x * (size_t)blockDim.x + threadIdx.x) >> 6);
  int l = threadIdx.x & 63;
  if (wid >= N) return;
  int o = off[wid];
  int dp = (deg[wid] + (ALIGN - 1)) & ~(ALIGN - 1);
  const uint* __restrict__ rows = (const uint*)hwb;
  float ax = 0.f, ay = 0.f;
  for (int i = 0; i < dp; i += 16) {
    int s[16];
    #pragma unroll
    for (int j = 0; j < 16; ++j) s[j] = ssrc[o + i + j];
    uint u[16];
    #pragma unroll
    for (int j = 0; j < 16; ++j) u[j] = rows[(size_t)s[j] * 64 + l];
    #pragma unroll
    for (int j = 0; j < 16; ++j) { ax += blo(u[j]); ay += bhi(u[j]); }
  }
  uint m = ((const uint*)im2b)[(size_t)wid * 64 + l];
  float rx = fmaxf(ax + blo(m), 0.f);
  float ry = fmaxf(ay + bhi(m), 0.f);
  ((uint*)hb)[(size_t)wid * 64 + l] = (uint)f2b(rx) | ((uint)f2b(ry) << 16);
}

// ------------- graph pooling: y[g] = relu(sum_{rows of g} actb[row]) ----------
__global__ void k_graphpool_b(const ushort* __restrict__ act, const int* __restrict__ gid,
                              float* __restrict__ out, int N) {
  __shared__ int s_lo, s_hi;
  __shared__ float red[8][32];
  int g = blockIdx.x;
  int chunk = blockIdx.y;
  int t = threadIdx.x;
  if (t == 0) {
    int lo = 0, hi = N;
    while (lo < hi) { int mid = (lo + hi) >> 1; if (gid[mid] < g) lo = mid + 1; else hi = mid; }
    s_lo = lo;
    lo = 0; hi = N;
    while (lo < hi) { int mid = (lo + hi) >> 1; if (gid[mid] < g + 1) lo = mid + 1; else hi = mid; }
    s_hi = lo;
  }
  __syncthreads();
  int c = chunk * 32 + (t & 31);
  int rid = t >> 5;
  float acc = 0.f;
  for (int r = s_lo + rid; r < s_hi; r += 8)
    acc += b2f(act[(size_t)r * 128 + c]);
  red[rid][t & 31] = acc;
  __syncthreads();
  if (rid == 0) {
    float s = 0.f;
    #pragma unroll
    for (int i = 0; i < 8; ++i) s += red[i][t & 31];
    out[(size_t)g * 128 + c] = fmaxf(s, 0.f);
  }
}

extern "C" void kernel_launch(void* const* d_in, const int* in_sizes, int n_in,
                              void* d_out, int out_size, void* d_ws, size_t ws_size,
                              hipStream_t stream) {
  const float* node_feat = (const float*)d_in[0];
  const float* edge_feat = (const float*)d_in[1];
  const int*   edge_src  = (const int*)d_in[2];
  const int*   edge_dst  = (const int*)d_in[3];
  const int*   graph_ids = (const int*)d_in[4];
  const float* w_n2l  = (const float*)d_in[5];
  const float* b_n2l  = (const float*)d_in[6];
  const float* w_e2l  = (const float*)d_in[7];
  const float* b_e2l  = (const float*)d_in[8];
  const float* w_conv = (const float*)d_in[9];
  const float* b_conv = (const float*)d_in[10];
  const float* w_out  = (const float*)d_in[11];
  const float* b_out  = (const float*)d_in[12];

  int N = in_sizes[0] / 128;
  int E = in_sizes[2];
  int Mpad = ((N + 128) / 128) * 128;          // >= N+1 (row N = pool sentinel)
  int cap = E + (ALIGN - 1) * N;               // padded slot capacity upper bound
  int nb = (N + 127) >> BSH;                   // buckets

  // ---- workspace carve ----
  ushort* Eb   = (ushort*)d_ws;                     // [Mpad][32]
  ushort* hb   = Eb   + (size_t)Mpad * 32;          // [Mpad][128]
  ushort* hwb  = hb   + (size_t)Mpad * 128;
  ushort* im2b = hwb  + (size_t)Mpad * 128;
  ushort* actb = im2b + (size_t)Mpad * 128;
  ushort* Wtn  = actb + (size_t)Mpad * 128;         // [128][160]
  ushort* Wtc  = Wtn + 128 * 160;                   // [128][128]
  ushort* Wto  = Wtc + 128 * 128;
  int* deg     = (int*)(Wto + 128 * 128);           // [N]
  int* off     = deg + N;                           // [N]
  int* bc      = off + N;                           // [nb]
  int* bpad    = bc + nb;
  int* bstart  = bpad + nb;
  int* pstartg = bstart + nb;
  int* bcur    = pstartg + nb;                      // [nb*16] (line-spread counters)
  uint* bq     = (uint*)(bcur + (size_t)nb * 16);   // [E] packed {dst&127, eid}
  int* ssrc    = (int*)(bq + E);                    // [cap]
  int* seid    = ssrc + cap;                        // [cap]

  hipMemsetAsync(bc, 0, (size_t)nb * sizeof(int), stream);

  int cgrid = (E + CHUNK - 1) / CHUNK;
  k_bhist<<<cgrid, 256, 0, stream>>>(edge_dst, bc, E, nb);
  k_scan<<<1, 256, 0, stream>>>(bc, bstart, bcur, nb);
  k_bscatter<<<cgrid, 256, 0, stream>>>(edge_dst, bcur, bq, E, nb);
  k_bcount<<<nb, 256, 0, stream>>>(bq, bstart, bc, deg, bpad, N);
  k_scan<<<1, 256, 0, stream>>>(bpad, pstartg, nullptr, nb);
  k_bplace<<<nb, 256, 0, stream>>>(bq, edge_src, bstart, bc, pstartg, deg, ssrc, seid, off, N);
  k_acc16f<<<Mpad / 4, 256, 0, stream>>>(edge_feat, off, deg, seid, Eb, N, Mpad);
  k_wt<<<dim3(128, 3), 256, 0, stream>>>(w_n2l, w_e2l, b_e2l, w_conv, w_out, Wtn, Wtc, Wto);

  int gB = Mpad / 128;
  k_mm0<<<gB, 256, 0, stream>>>(node_feat, Eb, Wtn, b_n2l, b_conv, hb, im2b, N);
  for (int it = 0; it < 3; ++it) {
    k_mm<1><<<gB, 256, 0, stream>>>(hb, Wtc, nullptr, hwb);
    k_pool_b<<<((size_t)N * 64 + 255) / 256, 256, 0, stream>>>(hwb, off, deg, ssrc, im2b, hb, N);
  }
  k_mm<2><<<gB, 256, 0, stream>>>(hb, Wto, b_out, actb);

  dim3 gp(out_size / 128, 4);
  k_graphpool_b<<<gp, 256, 0, stream>>>(actb, graph_ids, (float*)d_out, N);
}